// Round 12
// baseline (93.639 us; speedup 1.0000x reference)
//
#include <hip/hip_runtime.h>
#include <stdint.h>

#define BB 8
#define NN 2048
#define IND 10
#define QK 32

// Kernel 1: q[b][n][qd] = sum_d s[b,n,d]*Wq[qd,d]; k likewise.
// kt permuted for kernel 2's read: attn thread (wave w, lane i) owns cols
//   {512w + 4i + j : j=0..3} and {512w + 256 + 4i + j : j=0..3}.
// kt float4 index: (b*4+w)*4096 + (ev*8+jc)*64 + i, component c (qd=4ev+c).
__global__ __launch_bounds__(256) void qk_kernel(
    const float* __restrict__ s,
    const float* __restrict__ Wq, const float* __restrict__ Wk,
    float* __restrict__ q_ws, float* __restrict__ kt_ws) {
  int t = blockIdx.x * 256 + threadIdx.x;      // 0 .. B*N*QK-1 (exact)
  int b  = t >> 16;                            // N*QK = 65536
  int n  = (t >> 5) & (NN - 1);
  int qd = t & 31;
  const float* srow = s + (size_t)(b * NN + n) * IND;
  float acq = 0.f, ack = 0.f;
#pragma unroll
  for (int d = 0; d < IND; ++d) {
    float sv = srow[d];
    acq = fmaf(sv, Wq[qd * IND + d], acq);
    ack = fmaf(sv, Wk[qd * IND + d], ack);
  }
  q_ws[(size_t)(b * NN + n) * QK + qd] = acq;
  int w  = n >> 9;                 // wave (512 cols each)
  int m  = n & 511;
  int i  = (m & 255) >> 2;         // lane
  int jc = ((m < 256) ? 0 : 4) + (m & 3);
  int ev = qd >> 2, c = qd & 3;
  kt_ws[(((size_t)(b * 4 + w) * 4096) + (ev * 8 + jc) * 64 + i) * 4 + c] = ack;
}

// async global->LDS: lane's 16B from per-lane src -> uniform LDS base + lane*16
__device__ __forceinline__ void gload_lds16(const float* src, float* lds_dst) {
  __builtin_amdgcn_global_load_lds(
      reinterpret_cast<const __attribute__((address_space(1))) uint32_t*>(
          reinterpret_cast<uintptr_t>(src)),
      reinterpret_cast<__attribute__((address_space(3))) uint32_t*>(
          reinterpret_cast<uintptr_t>(lds_dst)),
      16, 0, 0);
}

// Kernel 2: one block = (batch, 8 rows), 256 threads. Thread (w,lane) owns
// cols {512w+4*lane+j} and {512w+256+4*lane+j}, j=0..3, for all 8 rows.
// GEMM identical to R9 (compiler-scheduled). G is streamed HBM->LDS in
// 2-row chunks via global_load_lds (zero VGPR -> no spill) with COUNTED
// vmcnt waits: chunk c+1 always stays in flight while chunk c is processed,
// so G's ~900cy HBM latency hides under the previous chunk's math. All G
// slices are wave-private (each wave writes/reads its own cols): no barriers
// until the final cross-wave reduce.
__global__ __launch_bounds__(256) void attn_kernel(
    const float* __restrict__ G,
    const float* __restrict__ q_ws, const float* __restrict__ kt_ws,
    float* __restrict__ out) {
  const int tid = threadIdx.x;
  const int b = blockIdx.y;
  const int r0 = blockIdx.x * 8;
  const int w = tid >> 6, lane = tid & 63;

  __shared__ float g_buf[2][2][4][512];  // 32 KB: [buf][rowInChunk][wave][col]
  __shared__ float q_lds[4][256];        // 4 KB, wave-private q tile copies
  __shared__ float red[4][8];

  // ---- wave-private q copy (8 rows x 32 = 256 contiguous floats) ----
  {
    const float* qb = q_ws + ((size_t)b * NN + r0) * QK;
    *(float4*)&q_lds[w][4 * lane] = *(const float4*)&qb[4 * lane];
  }

  const float4* kt =
      (const float4*)kt_ws + (size_t)(b * 4 + w) * 4096 + lane;
  const float* gb = G + ((size_t)b * NN + r0) * NN + 512 * w + 4 * lane;

  // ---- issue G chunks 0 (rows 0,1) and 1 (rows 2,3): 8 async loads ----
#pragma unroll
  for (int cr = 0; cr < 2; ++cr)
#pragma unroll
    for (int h = 0; h < 2; ++h)
      gload_lds16(gb + (size_t)cr * NN + 256 * h, &g_buf[0][cr][w][256 * h]);
#pragma unroll
  for (int cr = 0; cr < 2; ++cr)
#pragma unroll
    for (int h = 0; h < 2; ++h)
      gload_lds16(gb + (size_t)(2 + cr) * NN + 256 * h,
                  &g_buf[1][cr][w][256 * h]);

  // ---- GEMM: acc[r][j] = q[r0+r] . k[col(w,lane,j)]  (R9 verbatim) ----
  float acc[8][8];
#pragma unroll
  for (int r = 0; r < 8; ++r)
#pragma unroll
    for (int j = 0; j < 8; ++j) acc[r][j] = 0.f;

#pragma unroll
  for (int ev = 0; ev < 8; ++ev) {
    float q4[8][4];
#pragma unroll
    for (int r = 0; r < 8; ++r)
      *(float4*)q4[r] = *(const float4*)&q_lds[w][r * 32 + ev * 4];
#pragma unroll
    for (int j = 0; j < 8; ++j) {
      float4 k4 = kt[(ev * 8 + j) * 64];  // lane-coalesced
#pragma unroll
      for (int r = 0; r < 8; ++r) {
        acc[r][j] = fmaf(q4[r][0], k4.x, acc[r][j]);
        acc[r][j] = fmaf(q4[r][1], k4.y, acc[r][j]);
        acc[r][j] = fmaf(q4[r][2], k4.z, acc[r][j]);
        acc[r][j] = fmaf(q4[r][3], k4.w, acc[r][j]);
      }
    }
  }

  // ---- chunked epilogue: process 2 rows while the next chunk flies ----
  float rsum[8];

#define PROCESS_ROW(rr, bi, cr)                                          \
  {                                                                      \
    float gg[8];                                                         \
    *(float4*)&gg[0] = *(const float4*)&g_buf[bi][cr][w][4 * lane];      \
    *(float4*)&gg[4] = *(const float4*)&g_buf[bi][cr][w][256 + 4 * lane];\
    float sum = 0.f;                                                     \
    _Pragma("unroll")                                                    \
    for (int j = 0; j < 8; ++j) {                                        \
      float v = acc[rr][j];                                              \
      v = v * v * gg[j];                                                 \
      acc[rr][j] = v;                                                    \
      sum += v;                                                          \
    }                                                                    \
    _Pragma("unroll")                                                    \
    for (int off = 32; off >= 1; off >>= 1)                              \
      sum += __shfl_xor(sum, off, 64);                                   \
    rsum[rr] = sum;                                                      \
  }

  // chunk 0 ready (chunk 1's 4 loads may remain in flight)
  asm volatile("s_waitcnt vmcnt(4)" ::: "memory");
  __builtin_amdgcn_sched_barrier(0);
  PROCESS_ROW(0, 0, 0)
  PROCESS_ROW(1, 0, 1)
  // issue chunk 2 (rows 4,5) into buf 0 (just freed)
#pragma unroll
  for (int cr = 0; cr < 2; ++cr)
#pragma unroll
    for (int h = 0; h < 2; ++h)
      gload_lds16(gb + (size_t)(4 + cr) * NN + 256 * h,
                  &g_buf[0][cr][w][256 * h]);

  // chunk 1 ready (chunk 2 in flight)
  asm volatile("s_waitcnt vmcnt(4)" ::: "memory");
  __builtin_amdgcn_sched_barrier(0);
  PROCESS_ROW(2, 1, 0)
  PROCESS_ROW(3, 1, 1)
  // issue chunk 3 (rows 6,7) into buf 1
#pragma unroll
  for (int cr = 0; cr < 2; ++cr)
#pragma unroll
    for (int h = 0; h < 2; ++h)
      gload_lds16(gb + (size_t)(6 + cr) * NN + 256 * h,
                  &g_buf[1][cr][w][256 * h]);

  // chunk 2 ready (chunk 3 in flight)
  asm volatile("s_waitcnt vmcnt(4)" ::: "memory");
  __builtin_amdgcn_sched_barrier(0);
  PROCESS_ROW(4, 0, 0)
  PROCESS_ROW(5, 0, 1)

  // chunk 3 ready (nothing left in flight)
  asm volatile("s_waitcnt vmcnt(0)" ::: "memory");
  __builtin_amdgcn_sched_barrier(0);
  PROCESS_ROW(6, 1, 0)
  PROCESS_ROW(7, 1, 1)
#undef PROCESS_ROW

  // ---- cross-wave reduce ----
  if ((tid & 63) == 0) {
#pragma unroll
    for (int r = 0; r < 8; ++r) red[w][r] = rsum[r];
  }
  __syncthreads();

  float inv[8];
#pragma unroll
  for (int r = 0; r < 8; ++r) {
    float total = red[0][r] + red[1][r] + red[2][r] + red[3][r];
    inv[r] = 1.0f / (total + 1e-6f);
  }

  // ---- scale + coalesced store ----
  float* ob = out + ((size_t)b * NN + r0) * NN + 512 * w + 4 * lane;
#pragma unroll
  for (int r = 0; r < 8; ++r) {
    float4 o0, o1;
    o0.x = acc[r][0] * inv[r]; o0.y = acc[r][1] * inv[r];
    o0.z = acc[r][2] * inv[r]; o0.w = acc[r][3] * inv[r];
    o1.x = acc[r][4] * inv[r]; o1.y = acc[r][5] * inv[r];
    o1.z = acc[r][6] * inv[r]; o1.w = acc[r][7] * inv[r];
    *(float4*)(ob + (size_t)r * NN)       = o0;
    *(float4*)(ob + (size_t)r * NN + 256) = o1;
  }
}

extern "C" void kernel_launch(void* const* d_in, const int* in_sizes, int n_in,
                              void* d_out, int out_size, void* d_ws, size_t ws_size,
                              hipStream_t stream) {
  const float* s  = (const float*)d_in[0];
  const float* G  = (const float*)d_in[1];
  const float* Wq = (const float*)d_in[2];
  const float* Wk = (const float*)d_in[3];
  float* out = (float*)d_out;

  float* q_ws  = (float*)d_ws;                       // B*N*QK floats = 2 MB
  float* kt_ws = q_ws + (size_t)BB * NN * QK;        // another 2 MB

  qk_kernel<<<(BB * NN * QK) / 256, 256, 0, stream>>>(s, Wq, Wk, q_ws, kt_ws);

  dim3 grid(NN / 8, BB);
  attn_kernel<<<grid, 256, 0, stream>>>(G, q_ws, kt_ws, out);
}

// Round 13
// 64.667 us; speedup vs baseline: 1.4480x; 1.4480x over previous
//
#include <hip/hip_runtime.h>
#include <stdint.h>

#define BB 8
#define NN 2048
#define IND 10
#define QK 32

typedef float f32x4 __attribute__((ext_vector_type(4)));

// Kernel 1: q[b][n][qd] = sum_d s[b,n,d]*Wq[qd,d]; k likewise.
// kt permuted for kernel 2's read: attn thread (wave w, lane i) owns cols
//   {512w + 4i + j : j=0..3} and {512w + 256 + 4i + j : j=0..3}.
// kt float4 index: (b*4+w)*4096 + (ev*8+jc)*64 + i, component c (qd=4ev+c).
__global__ __launch_bounds__(256) void qk_kernel(
    const float* __restrict__ s,
    const float* __restrict__ Wq, const float* __restrict__ Wk,
    float* __restrict__ q_ws, float* __restrict__ kt_ws) {
  int t = blockIdx.x * 256 + threadIdx.x;      // 0 .. B*N*QK-1 (exact)
  int b  = t >> 16;                            // N*QK = 65536
  int n  = (t >> 5) & (NN - 1);
  int qd = t & 31;
  const float* srow = s + (size_t)(b * NN + n) * IND;
  float acq = 0.f, ack = 0.f;
#pragma unroll
  for (int d = 0; d < IND; ++d) {
    float sv = srow[d];
    acq = fmaf(sv, Wq[qd * IND + d], acq);
    ack = fmaf(sv, Wk[qd * IND + d], ack);
  }
  q_ws[(size_t)(b * NN + n) * QK + qd] = acq;
  int w  = n >> 9;                 // wave (512 cols each)
  int m  = n & 511;
  int i  = (m & 255) >> 2;         // lane
  int jc = ((m < 256) ? 0 : 4) + (m & 3);
  int ev = qd >> 2, c = qd & 3;
  kt_ws[(((size_t)(b * 4 + w) * 4096) + (ev * 8 + jc) * 64 + i) * 4 + c] = ack;
}

// Kernel 2: one block = (batch, 8 rows), 256 threads. Thread (w,lane) owns
// cols {512w+4*lane+j} and {512w+256+4*lane+j}, j=0..3, for all 8 rows.
// GEMM: explicit ka/kb k-double-buffer (R6's, proven spill-free at VGPR 136
// uncapped) so the next ev's 8 k-loads fly while the current ev's 256 FMAs
// run -- kills R9's serialized-k stall (64 x ~200cy = 2/3 of wave time).
// q is read per-row (4 transient regs) instead of holding q4[8][4] (32).
// Epilogue: R9 verbatim (stream G, no pinning). Out stores non-temporal so
// the 134 MB output stream doesn't evict G from L3.
__global__ __launch_bounds__(256) void attn_kernel(
    const float* __restrict__ G,
    const float* __restrict__ q_ws, const float* __restrict__ kt_ws,
    float* __restrict__ out) {
  const int tid = threadIdx.x;
  const int b = blockIdx.y;
  const int r0 = blockIdx.x * 8;
  const int w = tid >> 6, lane = tid & 63;

  __shared__ float q_lds[4][256];  // wave-private q tile copies (1 KB/wave)
  __shared__ float red[4][8];

  // ---- wave-private q copy (8 rows x 32 = 256 contiguous floats) ----
  {
    const float* qb = q_ws + ((size_t)b * NN + r0) * QK;
    *(float4*)&q_lds[w][4 * lane] = *(const float4*)&qb[4 * lane];
  }

  // ---- GEMM: acc[r][j] = q[r0+r] . k[col(w,lane,j)] ----
  float acc[8][8];
#pragma unroll
  for (int r = 0; r < 8; ++r)
#pragma unroll
    for (int j = 0; j < 8; ++j) acc[r][j] = 0.f;

  const float4* kt =
      (const float4*)kt_ws + (size_t)(b * 4 + w) * 4096 + lane;

  float4 ka[8], kb[8];
#pragma unroll
  for (int j = 0; j < 8; ++j) ka[j] = kt[j * 64];  // ev=0, lane-coalesced

#pragma unroll
  for (int ev = 0; ev < 8; ++ev) {
    if (ev < 7) {
#pragma unroll
      for (int j = 0; j < 8; ++j) kb[j] = kt[((ev + 1) * 8 + j) * 64];
    }
#pragma unroll
    for (int r = 0; r < 8; ++r) {
      float q4[4];
      *(float4*)q4 = *(const float4*)&q_lds[w][r * 32 + ev * 4];  // broadcast
#pragma unroll
      for (int j = 0; j < 8; ++j) {
        acc[r][j] = fmaf(q4[0], ka[j].x, acc[r][j]);
        acc[r][j] = fmaf(q4[1], ka[j].y, acc[r][j]);
        acc[r][j] = fmaf(q4[2], ka[j].z, acc[r][j]);
        acc[r][j] = fmaf(q4[3], ka[j].w, acc[r][j]);
      }
    }
#pragma unroll
    for (int j = 0; j < 8; ++j) ka[j] = kb[j];  // renamed away by unroll
  }

  // ---- stream G row-by-row: v = logits^2 * G, row partials, butterfly ----
  const float* gb = G + ((size_t)b * NN + r0) * NN + 512 * w + 4 * lane;
  float rsum[8];
#pragma unroll
  for (int r = 0; r < 8; ++r) {
    float gg[8];
    *(float4*)&gg[0] = *(const float4*)(gb + (size_t)r * NN);
    *(float4*)&gg[4] = *(const float4*)(gb + (size_t)r * NN + 256);
    float sum = 0.f;
#pragma unroll
    for (int j = 0; j < 8; ++j) {
      float v = acc[r][j];
      v = v * v * gg[j];
      acc[r][j] = v;
      sum += v;
    }
#pragma unroll
    for (int off = 32; off >= 1; off >>= 1) sum += __shfl_xor(sum, off, 64);
    rsum[r] = sum;
  }

  // ---- cross-wave reduce ----
  if ((tid & 63) == 0) {
#pragma unroll
    for (int r = 0; r < 8; ++r) red[w][r] = rsum[r];
  }
  __syncthreads();

  float inv[8];
#pragma unroll
  for (int r = 0; r < 8; ++r) {
    float total = red[0][r] + red[1][r] + red[2][r] + red[3][r];
    inv[r] = 1.0f / (total + 1e-6f);
  }

  // ---- scale + coalesced non-temporal store ----
  float* ob = out + ((size_t)b * NN + r0) * NN + 512 * w + 4 * lane;
#pragma unroll
  for (int r = 0; r < 8; ++r) {
    f32x4 o0, o1;
    o0.x = acc[r][0] * inv[r]; o0.y = acc[r][1] * inv[r];
    o0.z = acc[r][2] * inv[r]; o0.w = acc[r][3] * inv[r];
    o1.x = acc[r][4] * inv[r]; o1.y = acc[r][5] * inv[r];
    o1.z = acc[r][6] * inv[r]; o1.w = acc[r][7] * inv[r];
    __builtin_nontemporal_store(o0, (f32x4*)(ob + (size_t)r * NN));
    __builtin_nontemporal_store(o1, (f32x4*)(ob + (size_t)r * NN + 256));
  }
}

extern "C" void kernel_launch(void* const* d_in, const int* in_sizes, int n_in,
                              void* d_out, int out_size, void* d_ws, size_t ws_size,
                              hipStream_t stream) {
  const float* s  = (const float*)d_in[0];
  const float* G  = (const float*)d_in[1];
  const float* Wq = (const float*)d_in[2];
  const float* Wk = (const float*)d_in[3];
  float* out = (float*)d_out;

  float* q_ws  = (float*)d_ws;                       // B*N*QK floats = 2 MB
  float* kt_ws = q_ws + (size_t)BB * NN * QK;        // another 2 MB

  qk_kernel<<<(BB * NN * QK) / 256, 256, 0, stream>>>(s, Wq, Wk, q_ws, kt_ws);

  dim3 grid(NN / 8, BB);
  attn_kernel<<<grid, 256, 0, stream>>>(G, q_ws, kt_ws, out);
}

// Round 14
// 63.087 us; speedup vs baseline: 1.4843x; 1.0251x over previous
//
#include <hip/hip_runtime.h>
#include <stdint.h>

#define BB 8
#define NN 2048
#define IND 10
#define QK 32

typedef float f32x4 __attribute__((ext_vector_type(4)));

// Kernel 1: q[b][n][qd] = sum_d s[b,n,d]*Wq[qd,d]; k likewise.
// kt permuted for kernel 2's read: attn thread (wave w, lane i) owns cols
//   {512w + 4i + j : j=0..3} and {512w + 256 + 4i + j : j=0..3}.
// kt float4 index: (b*4+w)*4096 + (ev*8+jc)*64 + i, component c (qd=4ev+c).
__global__ __launch_bounds__(256) void qk_kernel(
    const float* __restrict__ s,
    const float* __restrict__ Wq, const float* __restrict__ Wk,
    float* __restrict__ q_ws, float* __restrict__ kt_ws) {
  int t = blockIdx.x * 256 + threadIdx.x;      // 0 .. B*N*QK-1 (exact)
  int b  = t >> 16;                            // N*QK = 65536
  int n  = (t >> 5) & (NN - 1);
  int qd = t & 31;
  const float* srow = s + (size_t)(b * NN + n) * IND;
  float acq = 0.f, ack = 0.f;
#pragma unroll
  for (int d = 0; d < IND; ++d) {
    float sv = srow[d];
    acq = fmaf(sv, Wq[qd * IND + d], acq);
    ack = fmaf(sv, Wk[qd * IND + d], ack);
  }
  q_ws[(size_t)(b * NN + n) * QK + qd] = acq;
  int w  = n >> 9;                 // wave (512 cols each)
  int m  = n & 511;
  int i  = (m & 255) >> 2;         // lane
  int jc = ((m < 256) ? 0 : 4) + (m & 3);
  int ev = qd >> 2, c = qd & 3;
  kt_ws[(((size_t)(b * 4 + w) * 4096) + (ev * 8 + jc) * 64 + i) * 4 + c] = ack;
}

// Kernel 2: one block = (batch, 8 rows), 256 threads. Thread (w,lane) owns
// cols {512w+4*lane+j} and {512w+256+4*lane+j}, j=0..3, for all 8 rows.
// GEMM: R13's ka/kb k-double-buffer (spill-free, compiler-scheduled).
// Epilogue: ALL 16 G float4s loaded into named registers first (64 transient
// regs; peak ~140 VGPR, uncapped -> no spill), one epilogue-local
// sched_barrier, then 8 rows of math+butterfly run against ready data.
// This removes the per-row ~900cy G-latency exposure that R13 only
// partially overlapped (VGPR=100 => compiler held ~2-4 loads in flight).
__global__ __launch_bounds__(256) void attn_kernel(
    const float* __restrict__ G,
    const float* __restrict__ q_ws, const float* __restrict__ kt_ws,
    float* __restrict__ out) {
  const int tid = threadIdx.x;
  const int b = blockIdx.y;
  const int r0 = blockIdx.x * 8;
  const int w = tid >> 6, lane = tid & 63;

  __shared__ float q_lds[4][256];  // wave-private q tile copies (1 KB/wave)
  __shared__ float red[4][8];

  // ---- wave-private q copy (8 rows x 32 = 256 contiguous floats) ----
  {
    const float* qb = q_ws + ((size_t)b * NN + r0) * QK;
    *(float4*)&q_lds[w][4 * lane] = *(const float4*)&qb[4 * lane];
  }

  // ---- GEMM: acc[r][j] = q[r0+r] . k[col(w,lane,j)] ----
  float acc[8][8];
#pragma unroll
  for (int r = 0; r < 8; ++r)
#pragma unroll
    for (int j = 0; j < 8; ++j) acc[r][j] = 0.f;

  const float4* kt =
      (const float4*)kt_ws + (size_t)(b * 4 + w) * 4096 + lane;

  float4 ka[8], kb[8];
#pragma unroll
  for (int j = 0; j < 8; ++j) ka[j] = kt[j * 64];  // ev=0, lane-coalesced

#pragma unroll
  for (int ev = 0; ev < 8; ++ev) {
    if (ev < 7) {
#pragma unroll
      for (int j = 0; j < 8; ++j) kb[j] = kt[((ev + 1) * 8 + j) * 64];
    }
#pragma unroll
    for (int r = 0; r < 8; ++r) {
      float q4[4];
      *(float4*)q4 = *(const float4*)&q_lds[w][r * 32 + ev * 4];  // broadcast
#pragma unroll
      for (int j = 0; j < 8; ++j) {
        acc[r][j] = fmaf(q4[0], ka[j].x, acc[r][j]);
        acc[r][j] = fmaf(q4[1], ka[j].y, acc[r][j]);
        acc[r][j] = fmaf(q4[2], ka[j].z, acc[r][j]);
        acc[r][j] = fmaf(q4[3], ka[j].w, acc[r][j]);
      }
    }
#pragma unroll
    for (int j = 0; j < 8; ++j) ka[j] = kb[j];  // renamed away by unroll
  }

  // ---- epilogue: prefetch ALL G into registers, then math ----
  const float* gb = G + ((size_t)b * NN + r0) * NN + 512 * w + 4 * lane;
  float4 g0[8], g1[8];
#pragma unroll
  for (int r = 0; r < 8; ++r) {
    g0[r] = *(const float4*)(gb + (size_t)r * NN);
    g1[r] = *(const float4*)(gb + (size_t)r * NN + 256);
  }
  __builtin_amdgcn_sched_barrier(0);  // loads above, math below (epilogue-local)

  float rsum[8];
#pragma unroll
  for (int r = 0; r < 8; ++r) {
    float gg[8];
    *(float4*)&gg[0] = g0[r];
    *(float4*)&gg[4] = g1[r];
    float sum = 0.f;
#pragma unroll
    for (int j = 0; j < 8; ++j) {
      float v = acc[r][j];
      v = v * v * gg[j];
      acc[r][j] = v;
      sum += v;
    }
#pragma unroll
    for (int off = 32; off >= 1; off >>= 1) sum += __shfl_xor(sum, off, 64);
    rsum[r] = sum;
  }

  // ---- cross-wave reduce ----
  if ((tid & 63) == 0) {
#pragma unroll
    for (int r = 0; r < 8; ++r) red[w][r] = rsum[r];
  }
  __syncthreads();

  float inv[8];
#pragma unroll
  for (int r = 0; r < 8; ++r) {
    float total = red[0][r] + red[1][r] + red[2][r] + red[3][r];
    inv[r] = 1.0f / (total + 1e-6f);
  }

  // ---- scale + coalesced non-temporal store ----
  float* ob = out + ((size_t)b * NN + r0) * NN + 512 * w + 4 * lane;
#pragma unroll
  for (int r = 0; r < 8; ++r) {
    f32x4 o0, o1;
    o0.x = acc[r][0] * inv[r]; o0.y = acc[r][1] * inv[r];
    o0.z = acc[r][2] * inv[r]; o0.w = acc[r][3] * inv[r];
    o1.x = acc[r][4] * inv[r]; o1.y = acc[r][5] * inv[r];
    o1.z = acc[r][6] * inv[r]; o1.w = acc[r][7] * inv[r];
    __builtin_nontemporal_store(o0, (f32x4*)(ob + (size_t)r * NN));
    __builtin_nontemporal_store(o1, (f32x4*)(ob + (size_t)r * NN + 256));
  }
}

extern "C" void kernel_launch(void* const* d_in, const int* in_sizes, int n_in,
                              void* d_out, int out_size, void* d_ws, size_t ws_size,
                              hipStream_t stream) {
  const float* s  = (const float*)d_in[0];
  const float* G  = (const float*)d_in[1];
  const float* Wq = (const float*)d_in[2];
  const float* Wk = (const float*)d_in[3];
  float* out = (float*)d_out;

  float* q_ws  = (float*)d_ws;                       // B*N*QK floats = 2 MB
  float* kt_ws = q_ws + (size_t)BB * NN * QK;        // another 2 MB

  qk_kernel<<<(BB * NN * QK) / 256, 256, 0, stream>>>(s, Wq, Wk, q_ws, kt_ws);

  dim3 grid(NN / 8, BB);
  attn_kernel<<<grid, 256, 0, stream>>>(G, q_ws, kt_ws, out);
}